// Round 4
// baseline (4143.824 us; speedup 1.0000x reference)
//
#include <hip/hip_runtime.h>
#include <hip/hip_fp16.h>

// LSTM forecaster: B=256, T=512, D_IN=64, H=1024, out = h_final @ Wout + bout.
// Persistent cooperative kernel, grid=256 (1 WG/CU), 8 waves/WG (512 thr).
// Round 4 vs round 3 (7.2us/step, h-exchange fabric-BW-bound):
//  - h loads are PLAIN CACHED half8 loads (L2 serves the 32-way same-XCD sharing);
//    coherence by one agent-scope ACQUIRE fence (L1+L2 inv) per WG per step, issued
//    by wave 0 after the barrier proves all h-stores reached the MALL.
//    (h stores remain bypass-atomic: only 2KB/WG, no wbl2 needed.)
//  - XCD-pair locality: m = xcd>>1 -> each m-group (the only WGs that exchange h)
//    lives on exactly 2 XCDs; 4 INDEPENDENT 64-WG barriers instead of 1x256.
//  - wave 0 = barrier wave (64 lanes poll 64 arrival words, ballot loop);
//    waves 2-3 fold x(t+1)@Wx into acc concurrently with the poll.
//  - v_rcp_f32 for sigmoid/tanh divides.

#define T_STEPS 512
#define HID 1024
#define GRID 256
#define NTHR 512

typedef __attribute__((ext_vector_type(8))) _Float16 half8;
typedef __attribute__((ext_vector_type(4))) float f32x4;
typedef __attribute__((ext_vector_type(2))) float f32x2;

__device__ __forceinline__ float sigm(float v) {
    return __builtin_amdgcn_rcpf(1.0f + __expf(-v));
}
__device__ __forceinline__ float tanh_fast(float v) {
    return 2.0f * __builtin_amdgcn_rcpf(1.0f + __expf(-2.0f * v)) - 1.0f;
}

// Pack W [1088][4096] f32 -> Wp fp16 [n(64)][kb(136)][col(64)][kin(8)]
// col c of group n maps to original column (c&3)*1024 + n*16 + (c>>2)  (gate-interleaved).
__global__ void pack_w(const float* __restrict__ W, _Float16* __restrict__ Wp) {
    int idx = blockIdx.x * 256 + threadIdx.x;
    const int total = 64 * 136 * 64;
    if (idx >= total) return;
    int col = idx & 63;
    int kb = (idx >> 6) % 136;
    int n = (idx >> 6) / 136;
    int oc = ((col & 3) << 10) + (n << 4) + (col >> 2);
    const float* src = W + (size_t)(kb * 8) * 4096 + oc;
    _Float16* dst = Wp + (size_t)idx * 8;
#pragma unroll
    for (int j = 0; j < 8; j++) dst[j] = (_Float16)src[(size_t)j * 4096];
}

__global__ void __launch_bounds__(NTHR, 2) lstm_persist(
    const float* __restrict__ x,      // [256][512][64] f32
    const _Float16* __restrict__ Wp,  // packed W fp16
    const float* __restrict__ bias,   // [4096] f32
    _Float16* __restrict__ hbuf,      // [2][128][256][8] fp16  (kb, b, kin)
    float* __restrict__ hfinal,       // [256][1024] f32
    unsigned int* bar)                // [4][64] arrival words, 64B apart
{
    __shared__ float P[4 * 64 * 64];  // 64 KiB, 4 planes, XOR-swizzled

    int wg = blockIdx.x;
    // XCD-pair mapping: dispatch round-robins XCDs (xcd = wg & 7).
    // m = xcd>>1 -> m-group (h-exchange domain) confined to 2 XCDs.
    int xcd = wg & 7;
    int m = xcd >> 1;                       // 0..3
    int n = ((xcd & 1) << 5) + (wg >> 3);   // 0..63
    int B0 = m << 6;
    int barId = (m << 6) + n;               // word index (x16 u32 spacing)

    int tid = threadIdx.x;
    int wave = tid >> 6;   // 0..7
    int lane = tid & 63;
    int l15 = lane & 15, l4 = lane >> 4;
    int bb = tid & 63;
    int u0 = tid >> 6;     // activation: units 2*u0, 2*u0+1

    // per-thread bias: q -> (b=bb, u=2*u0+q), gates i,f,g,o
    float breg[2][4];
#pragma unroll
    for (int q = 0; q < 2; q++) {
        int u = (u0 << 1) + q;
#pragma unroll
        for (int g = 0; g < 4; g++) breg[q][g] = bias[(g << 10) + (n << 4) + u];
    }

    float cst[2] = {0.f, 0.f};

    const size_t HB = (size_t)128 * 256 * 8;
    const _Float16* WpBase = Wp + (size_t)n * 136 * 64 * 8;

    // ---- W prologue: wave w owns h-chunks {2+w, 10+w, 18+w, 26+w} (covers 2..33),
    //      fragments register-resident for all 512 steps ----
    half8 wfr[4][4];
#pragma unroll
    for (int j = 0; j < 4; j++) {
        int kb = ((2 + wave + 8 * j) << 2) + l4;  // 8..135
        const _Float16* wp = WpBase + ((size_t)kb << 9);
#pragma unroll
        for (int nn = 0; nn < 4; nn++) wfr[j][nn] = *(const half8*)(wp + (((nn << 4) + l15) << 3));
    }

    f32x4 acc[4][4];
#pragma unroll
    for (int i = 0; i < 4; i++)
#pragma unroll
        for (int j = 0; j < 4; j++) acc[i][j] = (f32x4){0.f, 0.f, 0.f, 0.f};

    // x(tt) @ Wx into acc — waves 2,3 only (x chunk = wave-2, k in [32(w-2), 32(w-2)+32))
    auto XPREP = [&](int tt) {
        if (wave == 2 || wave == 3) {
            int kb = ((wave - 2) << 2) + l4;  // 0..7
            half8 bx[4];
            const _Float16* wp = WpBase + ((size_t)kb << 9);
#pragma unroll
            for (int nn = 0; nn < 4; nn++) bx[nn] = *(const half8*)(wp + (((nn << 4) + l15) << 3));
#pragma unroll
            for (int mm = 0; mm < 4; mm++) {
                const float* xp = x + ((size_t)(B0 + (mm << 4) + l15) * T_STEPS + tt) * 64 + (kb << 3);
                f32x4 lo = *(const f32x4*)xp;
                f32x4 hi = *(const f32x4*)(xp + 4);
                half8 v;
                v[0] = (_Float16)lo[0]; v[1] = (_Float16)lo[1];
                v[2] = (_Float16)lo[2]; v[3] = (_Float16)lo[3];
                v[4] = (_Float16)hi[0]; v[5] = (_Float16)hi[1];
                v[6] = (_Float16)hi[2]; v[7] = (_Float16)hi[3];
#pragma unroll
                for (int nn = 0; nn < 4; nn++)
                    acc[mm][nn] = __builtin_amdgcn_mfma_f32_16x16x32_f16(v, bx[nn], acc[mm][nn], 0, 0, 0);
            }
        }
    };

    XPREP(0);

    for (int t = 0; t < T_STEPS; t++) {
        const _Float16* cur = hbuf + (size_t)(t & 1) * HB;
        _Float16* nxt = hbuf + (size_t)((t + 1) & 1) * HB;

        // ---- h @ Wh: plain cached 16B loads (L2-shared within XCD), register W ----
#pragma unroll
        for (int j = 0; j < 4; j++) {
            int kb = ((2 + wave + 8 * j) << 2) + l4;  // 8..135
            const _Float16* hp = cur + (((size_t)(kb - 8) << 8) + B0 + l15) * 8;
            half8 ah[4];
#pragma unroll
            for (int mm = 0; mm < 4; mm++) ah[mm] = *(const half8*)(hp + (mm << 7));
#pragma unroll
            for (int mm = 0; mm < 4; mm++)
#pragma unroll
                for (int nn = 0; nn < 4; nn++)
                    acc[mm][nn] = __builtin_amdgcn_mfma_f32_16x16x32_f16(ah[mm], wfr[j][nn],
                                                                         acc[mm][nn], 0, 0, 0);
        }

        // ---- two-pass cross-wave reduction, 4 planes of 16KB, XOR-swizzled ----
        if (wave < 4) {
#pragma unroll
            for (int mm = 0; mm < 4; mm++)
#pragma unroll
                for (int nn = 0; nn < 4; nn++) {
                    int c = (nn << 4) + l15;
                    int bblk = (mm << 2) + l4;
                    int word = (((wave << 6) + c) << 6) + (((bblk ^ l15) & 15) << 2);
                    *(f32x4*)&P[word] = acc[mm][nn];
                }
        }
        __syncthreads();
        if (wave >= 4) {
            int pw = wave - 4;
#pragma unroll
            for (int mm = 0; mm < 4; mm++)
#pragma unroll
                for (int nn = 0; nn < 4; nn++) {
                    int c = (nn << 4) + l15;
                    int bblk = (mm << 2) + l4;
                    int word = (((pw << 6) + c) << 6) + (((bblk ^ l15) & 15) << 2);
                    f32x4 v = *(f32x4*)&P[word];
                    v += acc[mm][nn];
                    *(f32x4*)&P[word] = v;
                }
        }
        __syncthreads();

        // ---- activations: thread handles (b=bb, u=2*u0+q), q=0,1 ----
        union { _Float16 h2[2]; unsigned int u; } hs;
        float hvf[2];
#pragma unroll
        for (int q = 0; q < 2; q++) {
            int u = (u0 << 1) + q;
            float g4[4];
#pragma unroll
            for (int g = 0; g < 4; g++) {
                int c = (u << 2) + g;
                int word = (c << 6) + (((((bb >> 2) ^ c) & 15) << 2) | (bb & 3));
                float s = breg[q][g];
#pragma unroll
                for (int w = 0; w < 4; w++) s += P[(w << 12) + word];
                g4[g] = s;
            }
            float ig = sigm(g4[0]);
            float fg = sigm(g4[1]);
            float gg = tanh_fast(g4[2]);
            float og = sigm(g4[3]);
            float cv = fg * cst[q] + ig * gg;
            cst[q] = cv;
            float hv = og * tanh_fast(cv);
            hs.h2[q] = (_Float16)hv;
            hvf[q] = hv;
        }
        int ug0 = (n << 4) + (u0 << 1);
        if (t == T_STEPS - 1) {
            f32x2 hv2; hv2[0] = hvf[0]; hv2[1] = hvf[1];
            *(f32x2*)&hfinal[(size_t)(B0 + bb) * HID + ug0] = hv2;
            break;  // no barrier after last step
        }
        {
            // bypass-atomic store -> lands at MALL, readable after their acquire-inv
            unsigned int* dst =
                (unsigned int*)(nxt + ((size_t)(ug0 >> 3) * 256 + B0 + bb) * 8 + (ug0 & 7));
            __hip_atomic_store(dst, hs.u, __ATOMIC_RELAXED, __HIP_MEMORY_SCOPE_AGENT);
        }

        // ---- release: own h-stores ack'd at MALL, then all-waves sync ----
        asm volatile("s_waitcnt vmcnt(0)" ::: "memory");
        __syncthreads();

        // reset acc; waves 2,3 fold x(t+1) while wave 0 runs the barrier
#pragma unroll
        for (int i = 0; i < 4; i++)
#pragma unroll
            for (int j = 0; j < 4; j++) acc[i][j] = (f32x4){0.f, 0.f, 0.f, 0.f};
        XPREP(t + 1);

        if (wave == 0) {
            if (lane == 0)
                __hip_atomic_store(bar + ((size_t)barId << 4), (unsigned int)(t + 1),
                                   __ATOMIC_RELAXED, __HIP_MEMORY_SCOPE_AGENT);
            // 64 lanes poll the 64 arrival words of this m-group
            const unsigned int* ap = bar + ((size_t)((m << 6) + lane) << 4);
            bool done = false;
            while (!__all(done)) {
                if (!done) {
                    unsigned int v =
                        __hip_atomic_load(ap, __ATOMIC_RELAXED, __HIP_MEMORY_SCOPE_AGENT);
                    done = (v >= (unsigned int)(t + 1));
                }
                if (!done) __builtin_amdgcn_s_sleep(1);
            }
            // acquire: invalidate L1+L2 so next step's cached h loads see MALL data
            __builtin_amdgcn_fence(__ATOMIC_ACQUIRE, "agent");
            asm volatile("s_waitcnt vmcnt(0)" ::: "memory");
        }
        __syncthreads();
    }
}

// out[b][j] = bout[j] + sum_k hfinal[b][k] * Wout[k][j]   (256 blocks x 64 threads)
__global__ void proj_kernel(const float* __restrict__ hfinal, const float* __restrict__ Wout,
                            const float* __restrict__ bout, float* __restrict__ out) {
    int b = blockIdx.x;
    int l = threadIdx.x;
    float acc[24];
#pragma unroll
    for (int j = 0; j < 24; j++) acc[j] = 0.f;
    for (int i = 0; i < 16; i++) {
        int k = i * 64 + l;
        float h = hfinal[(size_t)b * HID + k];
        const float* wr = Wout + (size_t)k * 24;
#pragma unroll
        for (int j = 0; j < 24; j++) acc[j] += h * wr[j];
    }
    __shared__ float red[24][65];
#pragma unroll
    for (int j = 0; j < 24; j++) red[j][l] = acc[j];
    __syncthreads();
    if (l < 24) {
        float s = bout[l];
#pragma unroll
        for (int i = 0; i < 64; i++) s += red[l][i];
        out[b * 24 + l] = s;
    }
}

extern "C" void kernel_launch(void* const* d_in, const int* in_sizes, int n_in,
                              void* d_out, int out_size, void* d_ws, size_t ws_size,
                              hipStream_t stream) {
    const float* x = (const float*)d_in[0];     // [256][512][64]
    const float* W = (const float*)d_in[1];     // [1088][4096]
    const float* b = (const float*)d_in[2];     // [4096]
    const float* Wout = (const float*)d_in[3];  // [1024][24]
    const float* bout = (const float*)d_in[4];  // [24]
    float* out = (float*)d_out;

    char* ws = (char*)d_ws;
    _Float16* Wp = (_Float16*)ws;                                 // 8,912,896 B
    _Float16* hbuf = (_Float16*)(ws + 8912896);                   // 1,048,576 B
    float* hfinal = (float*)(ws + 8912896 + 1048576);             // 1,048,576 B
    unsigned int* bar = (unsigned int*)(ws + 8912896 + 2097152);  // 16,384 B

    // zero h buffer 0 (h_init = 0) and barrier words, every call (graph-replay safe)
    hipMemsetAsync(hbuf, 0, (size_t)128 * 256 * 8 * sizeof(_Float16), stream);
    hipMemsetAsync(bar, 0, 16384, stream);

    pack_w<<<(64 * 136 * 64 + 255) / 256, 256, 0, stream>>>(W, Wp);

    void* args[6];
    args[0] = (void*)&x;
    args[1] = (void*)&Wp;
    args[2] = (void*)&b;
    args[3] = (void*)&hbuf;
    args[4] = (void*)&hfinal;
    args[5] = (void*)&bar;
    hipLaunchCooperativeKernel((void*)lstm_persist, dim3(GRID), dim3(NTHR), args, 0, stream);

    proj_kernel<<<256, 64, 0, stream>>>(hfinal, Wout, bout, out);
}